// Round 1
// baseline (107.144 us; speedup 1.0000x reference)
//
#include <hip/hip_runtime.h>
#include <hip/hip_fp16.h>

#define NQ 12
#define DEPTH 8
#define NCLASS 10
#define BATCH 4096
#define LSTR 36      // LDS row stride in DWORDS (144 B, 16B-aligned; bank phase 4*l -> <=2-way)
#define WPB 2        // waves per block; LDS = 2*64*36*4 = 18432 B -> 8 blocks/CU = 16 waves/CU

// ---------------------------------------------------------------------------
// ONE wave per sample (4096 waves total -> 16 waves/CU, 2x the old occupancy).
// Statevector: 4096 fp16 amps = 64 lanes x 32 regs x 2 half2-slots.
//   PINNED bits (identical in both frames):  q0 <-> lane bit 5,  q11 <-> half2 slot.
//   Frame A: lane b4..b0 = q1..q5,  reg b4..b0 = q6..q10.
//   Frame B: lane b4..b0 = q6..q10, reg b4..b0 = q1..q5.
// Per layer:
//   RT1 (A->B): CNOTs split algebraically: P_A = {(6,7),(8,9),(10,11),(7,8),(9,10)}
//     (reg/slot-local in A) folded into the WRITE as static reg-permutation sigma
//     + compile-time slot swaps; P_T = lane-local CNOTs + cross (5,6) folded into
//     the READ addressing (4 base pointers + static row offsets).  Verified:
//     P_A(P_T(idx)) == composite of [even CNOTs then odd CNOTs] read-permutation.
//   shear q1..q5 (reg-local, frame B); shear q0 via v_permlane32_swap (VALU xor-32).
//   RT2 (B->A): plain b32 transpose.
//   shear q6..q10 (reg-local, frame A); shear q11 via half-swap + pk_fma (-t,+t).
// RY = c*[[1,-t],[t,1]]; c factors deferred into Call, applied as C^2 at the end.
// All DS intra-wave (private LDS region per wave, per-wave in-order) -> no barriers.
// ---------------------------------------------------------------------------

typedef unsigned int u32;

__device__ __forceinline__ u32 h2u(__half2 x){ return __builtin_bit_cast(u32, x); }
__device__ __forceinline__ __half2 u2h(u32 x){ return __builtin_bit_cast(__half2, x); }

// P_A fold at RT1 write: staged column c holds (maybe slot-swapped) v[sigma_pa(c)]
__device__ constexpr int sigma_pa(int c){
    const int c4=(c>>4)&1, c3=(c>>3)&1, c2=(c>>2)&1, c1=(c>>1)&1, c0=c&1;
    return (c4<<4) | ((c3^c4)<<3) | ((c2^c3)<<2) | ((c1^c2^c3)<<1) | (c0^c1);
}
__device__ constexpr int swap_pa(int c){ return (c ^ (c>>1)) & 1; }   // c0^c1

// P_T fold at RT1 read: static low-4 row bits for dst reg r (b4..b0 = q1..q5)
__device__ constexpr int rowlow_pt(int r){
    const int r4=(r>>4)&1, r3=(r>>3)&1, r2=(r>>2)&1, r1=(r>>1)&1, r0=r&1;
    return ((r3^r4)<<3) | ((r2^r3^r4)<<2) | ((r1^r2)<<1) | (r0^r1^r2);
}

// Shear over reg-bit mask M: a' = a - t*b ; b' = b + t*a  (1 pk_fma per output)
template<int M>
__device__ __forceinline__ void shear(__half2 (&v)[32], __half2 T2, __half2 Tn2){
#pragma unroll
    for(int r=0;r<32;++r){
        if(r & M) continue;
        const int r1 = r | M;
        const __half2 a = v[r], b = v[r1];
        v[r]  = __hfma2(Tn2, b, a);
        v[r1] = __hfma2(T2,  a, b);
    }
}

__global__ __launch_bounds__(WPB*64, 4) void vqc_kernel(const float* __restrict__ X,
                                                        const float* __restrict__ W,
                                                        float* __restrict__ out){
    __shared__ __align__(16) u32 lds[WPB*64*LSTR];

    const int lane = threadIdx.x & 63;
    const int wid  = threadIdx.x >> 6;
    const int s    = blockIdx.x*WPB + wid;     // sample id (one per wave)

    u32* Wb   = &lds[wid*64*LSTR];
    u32* wrow = &Wb[lane*LSTR];                // staging write base (16B aligned)
    const int l5  = lane >> 5;                 // q0 bit
    const int lo5 = lane & 31;
    // RT1 read base pointers, indexed [r4][r0]:
    //   row = (q0=l5)<<5 | (q1 = r4^l5)<<4 | rowlow_pt(r);  col = (lane&31) ^ (r0<<4)
    const u32* p00 = &Wb[(l5?0x30:0x00)*LSTR +  lo5      ];
    const u32* p01 = &Wb[(l5?0x30:0x00)*LSTR + (lo5^16)  ];
    const u32* p10 = &Wb[(l5?0x20:0x10)*LSTR +  lo5      ];
    const u32* p11 = &Wb[(l5?0x20:0x10)*LSTR + (lo5^16)  ];
    // RT2 read base: row = (lane&32)|r, col = lane&31
    const u32* rT2 = &Wb[(lane&32)*LSTR + lo5];

    // ---- data encoding: product state, frame A ----
    float cx[NQ], sx[NQ];
#pragma unroll
    for(int q=0;q<NQ;++q)
        __sincosf(0.5f*X[s*NQ+q] + 0.78539816339744831f, &sx[q], &cx[q]);

    float P = 1.0f;
#pragma unroll
    for(int q=0;q<6;++q) P *= ((lane>>(5-q))&1) ? sx[q] : cx[q];

    __half2 v[32];
    v[0] = __floats2half2_rn(P*cx[11], P*sx[11]);   // slot: lo=q11:0, hi=q11:1
#pragma unroll
    for(int lvl=0;lvl<5;++lvl){
        const int q = 10 - lvl;                     // q10..q6 on reg bits 0..4
        const __half2 SX = __float2half2_rn(sx[q]);
        const __half2 CX = __float2half2_rn(cx[q]);
#pragma unroll
        for(int j=0;j<16;++j){
            if(j >= (1<<lvl)) continue;
            v[j+(1<<lvl)] = __hmul2(v[j], SX);
            v[j]          = __hmul2(v[j], CX);
        }
    }

    float Call = 1.0f;   // product of cos(w/2) over all 96 gates (deferred scale)

#define PAV(c) (swap_pa(c) ? h2u(__lowhigh2highlow(v[sigma_pa(c)])) : h2u(v[sigma_pa(c)]))

    // ---- variational layers ----
#pragma unroll 1
    for(int k=0;k<DEPTH;++k){
        const float* Wk = &W[k*NQ];

        // RT1 write: frame-A state with reg/slot-local CNOTs (P_A) pre-applied
#pragma unroll
        for(int t=0;t<8;++t){
            uint4 w = make_uint4(PAV(4*t+0), PAV(4*t+1), PAV(4*t+2), PAV(4*t+3));
            *(uint4*)&wrow[4*t] = w;
        }
        // RT1 read: transpose + lane-side CNOTs + cross(5,6) fold
#pragma unroll
        for(int r=0;r<32;++r){
            const u32* pp = (r&16) ? ((r&1)?p11:p10) : ((r&1)?p01:p00);
            v[r] = u2h(pp[rowlow_pt(r)*LSTR]);
        }

        // shear q1..q5 (frame B: q -> reg bit (5-q))
        {
            float cw, sw;
#pragma unroll
            for(int q=1;q<6;++q){
                __sincosf(0.5f*Wk[q], &sw, &cw);
                Call *= cw;
                const float tq = sw/cw;
                const __half2 T2  = __floats2half2_rn(tq, tq);
                const __half2 Tn2 = __floats2half2_rn(-tq, -tq);
                switch(q){
                    case 1: shear<16>(v,T2,Tn2); break;
                    case 2: shear<8>(v,T2,Tn2);  break;
                    case 3: shear<4>(v,T2,Tn2);  break;
                    case 4: shear<2>(v,T2,Tn2);  break;
                    case 5: shear<1>(v,T2,Tn2);  break;
                }
            }
        }

        // shear q0 (lane bit 5, both frames) via v_permlane32_swap (VALU pipe)
        {
            float cw, sw;
            __sincosf(0.5f*Wk[0], &sw, &cw);
            Call *= cw;
            const float tq = sw/cw;
            const __half2 Tp = __floats2half2_rn(tq, tq);
            const __half2 Tn = __floats2half2_rn(-tq, -tq);
            const __half2 Tsgn = l5 ? Tp : Tn;   // b-side: +t, a-side: -t
#pragma unroll
            for(int r=0;r<32;++r){
                u32 a = h2u(v[r]), b = a;
                // a[32:63] <-> b[0:31]:  a = {v_lo, v_lo}, b = {v_hi, v_hi}
                asm("v_permlane32_swap_b32 %0, %1" : "+v"(a), "+v"(b));
                const u32 x = l5 ? a : b;        // xor-32 partner of v[r]
                v[r] = __hfma2(Tsgn, u2h(x), v[r]);
            }
        }

        // RT2: plain transpose B->A
#pragma unroll
        for(int t=0;t<8;++t){
            uint4 w = make_uint4(h2u(v[4*t]), h2u(v[4*t+1]), h2u(v[4*t+2]), h2u(v[4*t+3]));
            *(uint4*)&wrow[4*t] = w;
        }
#pragma unroll
        for(int r=0;r<32;++r) v[r] = u2h(rT2[r*LSTR]);

        // shear q6..q10 (frame A: q -> reg bit (10-q)) + slot shear q11
        {
            float cw, sw;
#pragma unroll
            for(int q=6;q<11;++q){
                __sincosf(0.5f*Wk[q], &sw, &cw);
                Call *= cw;
                const float tq = sw/cw;
                const __half2 T2  = __floats2half2_rn(tq, tq);
                const __half2 Tn2 = __floats2half2_rn(-tq, -tq);
                switch(q){
                    case 6:  shear<16>(v,T2,Tn2); break;
                    case 7:  shear<8>(v,T2,Tn2);  break;
                    case 8:  shear<4>(v,T2,Tn2);  break;
                    case 9:  shear<2>(v,T2,Tn2);  break;
                    case 10: shear<1>(v,T2,Tn2);  break;
                }
            }
            __sincosf(0.5f*Wk[11], &sw, &cw);
            Call *= cw;
            const float tq = sw/cw;
            const __half2 Tpm = __floats2half2_rn(-tq, tq); // lo' = lo - t*hi; hi' = hi + t*lo
#pragma unroll
            for(int r=0;r<32;++r)
                v[r] = __hfma2(Tpm, __lowhigh2highlow(v[r]), v[r]);
        }
    }
#undef PAV

    // ---- measurement (fp32), frame A ----
    const float C2 = Call*Call;
    float Sall = 0.f, Tb[4] = {0.f,0.f,0.f,0.f};  // Tb[j]: sign on reg bit (4-j) = q(6+j)
#pragma unroll
    for(int r=0;r<32;++r){
        const float2 f = __half22float2(v[r]);
        const float c2 = f.x*f.x + f.y*f.y;       // slot (q11) summed out
        Sall += c2;
        Tb[0] += ((r>>4)&1) ? -c2 : c2;
        Tb[1] += ((r>>3)&1) ? -c2 : c2;
        Tb[2] += ((r>>2)&1) ? -c2 : c2;
        Tb[3] += ((r>>1)&1) ? -c2 : c2;
    }
    Sall *= C2;
#pragma unroll
    for(int j=0;j<4;++j) Tb[j] *= C2;

    float o[NCLASS];
#pragma unroll
    for(int p=0;p<6;++p){        // qubit p on lane bit (5-p)
        float rr = (((lane>>(5-p))&1) ? -Sall : Sall);
#pragma unroll
        for(int m=0;m<6;++m) rr += __shfl_xor(rr, 1<<m, 64);
        o[p] = rr;
    }
#pragma unroll
    for(int p=6;p<NCLASS;++p){   // qubit p on reg bit (10-p)
        float rr = Tb[p-6];
#pragma unroll
        for(int m=0;m<6;++m) rr += __shfl_xor(rr, 1<<m, 64);
        o[p] = rr;
    }

    if(lane == 0){
#pragma unroll
        for(int p=0;p<NCLASS;++p) out[s*NCLASS+p] = o[p];
    }
}

extern "C" void kernel_launch(void* const* d_in, const int* in_sizes, int n_in,
                              void* d_out, int out_size, void* d_ws, size_t ws_size,
                              hipStream_t stream){
    const float* X = (const float*)d_in[0];
    const float* W = (const float*)d_in[1];
    float* out     = (float*)d_out;
    (void)in_sizes; (void)n_in; (void)out_size; (void)d_ws; (void)ws_size;

    dim3 grid(BATCH / WPB);     // one sample per wave, WPB waves per block
    dim3 block(WPB * 64);
    hipLaunchKernelGGL(vqc_kernel, grid, block, 0, stream, X, W, out);
}

// Round 4
// 106.966 us; speedup vs baseline: 1.0017x; 1.0017x over previous
//
#include <hip/hip_runtime.h>
#include <hip/hip_fp16.h>

#define NQ 12
#define DEPTH 8
#define NCLASS 10
#define BATCH 4096
#define LSTR 36      // LDS row stride in DWORDS (144 B, 16B-aligned; bank phase 4*l -> <=2-way)
#define WPB 2        // waves per block; LDS = 2*64*36*4 = 18432 B -> 8 blocks/CU = 16 waves/CU

// ---------------------------------------------------------------------------
// ONE wave per sample. Statevector: 4096 fp16 amps = 64 lanes x 32 regs x 2 slots.
//   PINNED bits (both frames):  q0 <-> lane bit 5,  q11 <-> half2 slot.
//   Frame A: lane b4..b0 = q1..q5,  reg b4..b0 = q6..q10.
//   Frame B: lane b4..b0 = q6..q10, reg b4..b0 = q1..q5.
// Per layer: RT1 (A->B, CNOTs folded: P_A into write as static reg-perm sigma +
// slot swaps; lane-side + cross(5,6) into read addressing), shear q1..q5 (reg),
// q0 (v_permlane32_swap), RT2 (plain transpose), shear q6..q10 (reg), q11 (slot).
// RY = c*[[1,-t],[t,1]]; all c factors -> global C^2 applied at measurement.
//
// ROUND 4: isolation experiment. Rounds 2+3 failed IDENTICALLY (absmax 6.64e-2)
// with two different constants mechanisms -> suspect set is the code shared by
// both: {grouped reads, fdot2, XOR-derived constants}. This round = round-1
// source verbatim + ONLY the grouped-read change (ds_read2_b32 formation via
// laundered 8-row base offsets). Constants and measurement are exactly round-1.
// All DS intra-wave (private region per wave, per-wave in-order) -> no barriers.
// ---------------------------------------------------------------------------

typedef unsigned int u32;

__device__ __forceinline__ u32 h2u(__half2 x){ return __builtin_bit_cast(u32, x); }
__device__ __forceinline__ __half2 u2h(u32 x){ return __builtin_bit_cast(__half2, x); }

// P_A fold at RT1 write: staged column c holds (maybe slot-swapped) v[sigma_pa(c)]
__device__ constexpr int sigma_pa(int c){
    const int c4=(c>>4)&1, c3=(c>>3)&1, c2=(c>>2)&1, c1=(c>>1)&1, c0=c&1;
    return (c4<<4) | ((c3^c4)<<3) | ((c2^c3)<<2) | ((c1^c2^c3)<<1) | (c0^c1);
}
__device__ constexpr int swap_pa(int c){ return (c ^ (c>>1)) & 1; }   // c0^c1

// P_T fold at RT1 read: static low-4 row bits for dst reg r (b4..b0 = q1..q5)
__device__ constexpr int rowlow_pt(int r){
    const int r4=(r>>4)&1, r3=(r>>3)&1, r2=(r>>2)&1, r1=(r>>1)&1, r0=r&1;
    return ((r3^r4)<<3) | ((r2^r3^r4)<<2) | ((r1^r2)<<1) | (r0^r1^r2);
}

// Shear over reg-bit mask M: a' = a - t*b ; b' = b + t*a  (1 pk_fma per output)
template<int M>
__device__ __forceinline__ void shear(__half2 (&v)[32], __half2 T2, __half2 Tn2){
#pragma unroll
    for(int r=0;r<32;++r){
        if(r & M) continue;
        const int r1 = r | M;
        const __half2 a = v[r], b = v[r1];
        v[r]  = __hfma2(Tn2, b, a);
        v[r1] = __hfma2(T2,  a, b);
    }
}

__global__ __launch_bounds__(WPB*64, 4) void vqc_kernel(const float* __restrict__ X,
                                                        const float* __restrict__ W,
                                                        float* __restrict__ out){
    __shared__ __align__(16) u32 lds[WPB*64*LSTR];

    const int lane = threadIdx.x & 63;
    const int wid  = threadIdx.x >> 6;
    const int s    = blockIdx.x*WPB + wid;     // sample id (one per wave)

    u32* Wb   = &lds[wid*64*LSTR];
    u32* wrow = &Wb[lane*LSTR];                // staging write base (16B aligned)
    const int l5  = lane >> 5;                 // q0 bit
    const int lo5 = lane & 31;

    // Opaque 8-row offset: distinct DS base VGPRs so the backend can pair
    // same-base reads (dword offsets <= 252) into ds_read2_b32.
    int off8 = 8*LSTR;
    asm("" : "+v"(off8));

    // RT1 read base pointers, indexed [r4][r0] (+ high-8-row variants):
    //   row = (q0=l5)<<5 | (q1 = r4^l5)<<4 | rowlow_pt(r);  col = (lane&31) ^ (r0<<4)
    const u32* p00 = &Wb[(l5?0x30:0x00)*LSTR +  lo5      ];
    const u32* p01 = &Wb[(l5?0x30:0x00)*LSTR + (lo5^16)  ];
    const u32* p10 = &Wb[(l5?0x20:0x10)*LSTR +  lo5      ];
    const u32* p11 = &Wb[(l5?0x20:0x10)*LSTR + (lo5^16)  ];
    const u32* p00h = p00 + off8;
    const u32* p01h = p01 + off8;
    const u32* p10h = p10 + off8;
    const u32* p11h = p11 + off8;
    // RT2 read bases: row = (lane&32)|r, col = lane&31; 4 chunks of 8 rows
    const u32* rT2b0 = &Wb[(lane&32)*LSTR + lo5];
    const u32* rT2b1 = rT2b0 + off8;
    const u32* rT2b2 = rT2b1 + off8;
    const u32* rT2b3 = rT2b2 + off8;

    // ---- data encoding: product state, frame A ----
    float cx[NQ], sx[NQ];
#pragma unroll
    for(int q=0;q<NQ;++q)
        __sincosf(0.5f*X[s*NQ+q] + 0.78539816339744831f, &sx[q], &cx[q]);

    float P = 1.0f;
#pragma unroll
    for(int q=0;q<6;++q) P *= ((lane>>(5-q))&1) ? sx[q] : cx[q];

    __half2 v[32];
    v[0] = __floats2half2_rn(P*cx[11], P*sx[11]);   // slot: lo=q11:0, hi=q11:1
#pragma unroll
    for(int lvl=0;lvl<5;++lvl){
        const int q = 10 - lvl;                     // q10..q6 on reg bits 0..4
        const __half2 SX = __float2half2_rn(sx[q]);
        const __half2 CX = __float2half2_rn(cx[q]);
#pragma unroll
        for(int j=0;j<16;++j){
            if(j >= (1<<lvl)) continue;
            v[j+(1<<lvl)] = __hmul2(v[j], SX);
            v[j]          = __hmul2(v[j], CX);
        }
    }

    float Call = 1.0f;   // product of cos(w/2) over all gates (deferred scale)

#define PAV(c) (swap_pa(c) ? h2u(__lowhigh2highlow(v[sigma_pa(c)])) : h2u(v[sigma_pa(c)]))

    // ---- variational layers ----
#pragma unroll 1
    for(int k=0;k<DEPTH;++k){
        const float* Wk = &W[k*NQ];

        // RT1 write: frame-A state with reg/slot-local CNOTs (P_A) pre-applied
#pragma unroll
        for(int t=0;t<8;++t){
            uint4 w = make_uint4(PAV(4*t+0), PAV(4*t+1), PAV(4*t+2), PAV(4*t+3));
            *(uint4*)&wrow[4*t] = w;
        }
        // RT1 read: transpose + lane-side CNOTs + cross(5,6) fold, grouped by
        // (r4, r0, rowlow bit3) -> 4 reads per base, dword offsets <= 252
#pragma unroll
        for(int g=0; g<8; ++g){
            const int r4 = g>>2, r0 = (g>>1)&1, h = g&1;
            const u32* pb =
                (r4==0) ? (r0==0 ? (h? p00h:p00) : (h? p01h:p01))
                        : (r0==0 ? (h? p10h:p10) : (h? p11h:p11));
#pragma unroll
            for(int r=0;r<32;++r){
                if(((r>>4)&1)!=r4 || (r&1)!=r0 || ((rowlow_pt(r)>>3)&1)!=h) continue;
                v[r] = u2h(pb[(rowlow_pt(r)&7)*LSTR]);
            }
        }

        // shear q1..q5 (frame B: q -> reg bit (5-q))
        {
            float cw, sw;
#pragma unroll
            for(int q=1;q<6;++q){
                __sincosf(0.5f*Wk[q], &sw, &cw);
                Call *= cw;
                const float t = sw/cw;
                const __half2 T2  = __floats2half2_rn(t, t);
                const __half2 Tn2 = __floats2half2_rn(-t, -t);
                switch(q){
                    case 1: shear<16>(v,T2,Tn2); break;
                    case 2: shear<8>(v,T2,Tn2);  break;
                    case 3: shear<4>(v,T2,Tn2);  break;
                    case 4: shear<2>(v,T2,Tn2);  break;
                    case 5: shear<1>(v,T2,Tn2);  break;
                }
            }
        }

        // shear q0 (lane bit 5, both frames) via v_permlane32_swap (VALU pipe)
        {
            float cw, sw;
            __sincosf(0.5f*Wk[0], &sw, &cw);
            Call *= cw;
            const float t = sw/cw;
            const __half2 Tp = __floats2half2_rn(t, t);
            const __half2 Tn = __floats2half2_rn(-t, -t);
            const __half2 Tsgn = l5 ? Tp : Tn;   // b-side: +t, a-side: -t
#pragma unroll
            for(int r=0;r<32;++r){
                u32 a = h2u(v[r]), b = a;
                // after swap: a = lo-half broadcast, b = hi-half broadcast
                asm("v_permlane32_swap_b32 %0, %1" : "+v"(a), "+v"(b));
                const u32 x = l5 ? a : b;        // xor-32 partner of v[r]
                v[r] = __hfma2(Tsgn, u2h(x), v[r]);
            }
        }

        // RT2: plain transpose B->A
#pragma unroll
        for(int t=0;t<8;++t){
            uint4 w = make_uint4(h2u(v[4*t]), h2u(v[4*t+1]), h2u(v[4*t+2]), h2u(v[4*t+3]));
            *(uint4*)&wrow[4*t] = w;
        }
#pragma unroll
        for(int c=0;c<4;++c){
            const u32* pr = (c==0)? rT2b0 : (c==1)? rT2b1 : (c==2)? rT2b2 : rT2b3;
#pragma unroll
            for(int j=0;j<8;++j) v[c*8+j] = u2h(pr[j*LSTR]);
        }

        // shear q6..q10 (frame A: q -> reg bit (10-q)) + slot shear q11
        {
            float cw, sw;
#pragma unroll
            for(int q=6;q<11;++q){
                __sincosf(0.5f*Wk[q], &sw, &cw);
                Call *= cw;
                const float t = sw/cw;
                const __half2 T2  = __floats2half2_rn(t, t);
                const __half2 Tn2 = __floats2half2_rn(-t, -t);
                switch(q){
                    case 6:  shear<16>(v,T2,Tn2); break;
                    case 7:  shear<8>(v,T2,Tn2);  break;
                    case 8:  shear<4>(v,T2,Tn2);  break;
                    case 9:  shear<2>(v,T2,Tn2);  break;
                    case 10: shear<1>(v,T2,Tn2);  break;
                }
            }
            __sincosf(0.5f*Wk[11], &sw, &cw);
            Call *= cw;
            const float t = sw/cw;
            const __half2 Tpm = __floats2half2_rn(-t, t); // lo'=lo-t*hi; hi'=hi+t*lo
#pragma unroll
            for(int r=0;r<32;++r)
                v[r] = __hfma2(Tpm, __lowhigh2highlow(v[r]), v[r]);
        }
    }
#undef PAV

    // ---- measurement (fp32), frame A ----
    const float C2 = Call*Call;
    float Sall = 0.f, Tb[4] = {0.f,0.f,0.f,0.f};  // Tb[j]: sign on reg bit (4-j) = q(6+j)
#pragma unroll
    for(int r=0;r<32;++r){
        const float2 f = __half22float2(v[r]);
        const float c2 = f.x*f.x + f.y*f.y;       // slot (q11) summed out
        Sall += c2;
        Tb[0] += ((r>>4)&1) ? -c2 : c2;
        Tb[1] += ((r>>3)&1) ? -c2 : c2;
        Tb[2] += ((r>>2)&1) ? -c2 : c2;
        Tb[3] += ((r>>1)&1) ? -c2 : c2;
    }
    Sall *= C2;
#pragma unroll
    for(int j=0;j<4;++j) Tb[j] *= C2;

    float o[NCLASS];
#pragma unroll
    for(int p=0;p<6;++p){        // qubit p on lane bit (5-p)
        float rr = (((lane>>(5-p))&1) ? -Sall : Sall);
#pragma unroll
        for(int m=0;m<6;++m) rr += __shfl_xor(rr, 1<<m, 64);
        o[p] = rr;
    }
#pragma unroll
    for(int p=6;p<NCLASS;++p){   // qubit p on reg bit (10-p)
        float rr = Tb[p-6];
#pragma unroll
        for(int m=0;m<6;++m) rr += __shfl_xor(rr, 1<<m, 64);
        o[p] = rr;
    }

    if(lane == 0){
#pragma unroll
        for(int p=0;p<NCLASS;++p) out[s*NCLASS+p] = o[p];
    }
}

extern "C" void kernel_launch(void* const* d_in, const int* in_sizes, int n_in,
                              void* d_out, int out_size, void* d_ws, size_t ws_size,
                              hipStream_t stream){
    const float* X = (const float*)d_in[0];
    const float* W = (const float*)d_in[1];
    float* out     = (float*)d_out;
    (void)in_sizes; (void)n_in; (void)out_size; (void)d_ws; (void)ws_size;

    dim3 grid(BATCH / WPB);     // one sample per wave, WPB waves per block
    dim3 block(WPB * 64);
    hipLaunchKernelGGL(vqc_kernel, grid, block, 0, stream, X, W, out);
}

// Round 8
// 97.738 us; speedup vs baseline: 1.0962x; 1.0944x over previous
//
#include <hip/hip_runtime.h>
#include <hip/hip_fp16.h>

#define NQ 12
#define DEPTH 8
#define NCLASS 10
#define BATCH 4096
#define LSTRIDE 68   // LDS row stride in DWORDS (272 B; 16B-aligned rows; bank phase 4l -> <=2-way)
#define WPB 2        // waves per block; 2 samples/wave; LDS = 2*64*68*4 = 34816 B

// ---------------------------------------------------------------------------
// One wave per TWO samples (r0 base, 50.3us session-best). Statevector
// amplitude (12-bit index) for both samples packed as __half2 in v[64]/lane.
// Frame A: qubit q in 0..5  <-> lane bit (5-q);  q in 6..11 <-> reg bit (11-q)
// Frame B: qubit q in 0..5  <-> reg  bit (5-q);  q in 6..11 <-> lane bit (11-q)
// Per layer: RT1 (CNOTs folded, A->B), shear-RY q0..5 (reg-local), RT2 (plain
// transpose B->A), shear-RY q6..11 (reg-local). RY = c*[[1,-t],[t,1]], C=prod c
// deferred to C^2 at measurement.
//
// ROUND 8: constants path FROZEN at the r0/r1/r4 in-loop __sincosf form (five
// variants of precomputed/hoisted/small-angle constants all failed ~0.07;
// mechanism undiagnosable from bench evidence — do not touch).
// Change vs r0 (single variable): chunked transpose reads with laundered
// 4-row bases -> guaranteed ds_read2_b32 pairing. Proof: hfun is GF(2)-linear;
// for dst quad {4t..4t+3} only rb0,rb1 vary -> only hfun low-2 bits vary ->
// all 4 reads hit one aligned 4-row window, 2 even-col + 2 odd-col -> one
// read2 per (window,parity). RT2 linear: offsets {0,68},{136,204} dwords <=255.
// All DS intra-wave (private region per wave, DS in-order) -> no barriers.
// ---------------------------------------------------------------------------

__device__ __forceinline__ uint32_t h2u(__half2 x) { return __builtin_bit_cast(uint32_t, x); }
__device__ __forceinline__ __half2 u2h(uint32_t x) { return __builtin_bit_cast(__half2, x); }

__device__ constexpr int hfun(int r) {  // src row (old lane) for RT1 output reg r
    const int rb5 = (r >> 5) & 1, rb4 = (r >> 4) & 1, rb3 = (r >> 3) & 1;
    const int rb2 = (r >> 2) & 1, rb1 = (r >> 1) & 1, rb0 = r & 1;
    const int c0 = rb5;
    const int c1 = rb4 ^ rb5;
    const int c2 = rb3 ^ rb4;
    const int c3 = rb2 ^ rb3 ^ rb4;
    const int c4 = rb1 ^ rb2;
    const int c5 = rb0 ^ rb1 ^ rb2;
    return (c0 << 5) | (c1 << 4) | (c2 << 3) | (c3 << 2) | (c4 << 1) | c5;
}

// Shear rotation over reg-bit mask M in packed fp16 (both samples at once):
// a' = a - t*b ; b' = b + t*a   (1 pk_fma per output)
template <int M>
__device__ __forceinline__ void shear16(__half2 (&v)[64], __half2 T2, __half2 Tn2) {
#pragma unroll
    for (int r = 0; r < 64; ++r) {
        if (r & M) continue;
        const int r1 = r | M;
        const __half2 a = v[r], b = v[r1];
        v[r]  = __hfma2(Tn2, b, a);
        v[r1] = __hfma2(T2, a, b);
    }
}

__global__ __launch_bounds__(WPB * 64) void vqc_kernel(const float* __restrict__ X,
                                                       const float* __restrict__ W,
                                                       float* __restrict__ out) {
    __shared__ __align__(16) uint32_t lds[WPB * 64 * LSTRIDE];

    const int lane = threadIdx.x & 63;
    const int wid  = threadIdx.x >> 6;
    const int gw   = blockIdx.x * WPB + wid;   // global wave id
    const int s0   = 2 * gw, s1 = s0 + 1;      // the two samples
    const int l    = lane;

    uint32_t* Wb   = &lds[wid * 64 * LSTRIDE];
    uint32_t* wrow = &Wb[l * LSTRIDE];                 // staging write base (16B aligned)
    const int G = l ^ (l >> 1) ^ ((l >> 2) & 5);       // RT1 src col (lane-local CNOTs folded)
    const uint32_t* colA = &Wb[G];                     // r even (q5=0)
    const uint32_t* colB = &Wb[G ^ 0x30];              // r odd  (q5=1): CNOT(5,6) col flip
    const uint32_t* rT2  = &Wb[l];                     // RT2 read base

    // Laundered 4-row offset: forces distinct VGPR bases with small (<=255
    // dword) per-read immediates so the backend pairs into ds_read2_b32.
    int off4 = 4 * LSTRIDE;
    asm("" : "+v"(off4));
    const uint32_t *bA[16], *bB[16], *bT[16];
    {
        const uint32_t* a  = colA;
        const uint32_t* b  = colB;
        const uint32_t* t2 = rT2;
#pragma unroll
        for (int c = 0; c < 16; ++c) {
            bA[c] = a; bB[c] = b; bT[c] = t2;
            a += off4; b += off4; t2 += off4;
        }
    }

    // ---- data encoding: product state for both samples, frame A ----
    float cx0[NQ], sx0[NQ], cx1[NQ], sx1[NQ];
#pragma unroll
    for (int q = 0; q < NQ; ++q) {
        __sincosf(0.5f * X[s0 * NQ + q] + 0.78539816339744831f, &sx0[q], &cx0[q]);
        __sincosf(0.5f * X[s1 * NQ + q] + 0.78539816339744831f, &sx1[q], &cx1[q]);
    }
    float P0 = 1.0f, P1 = 1.0f;
#pragma unroll
    for (int q = 0; q < 6; ++q) {
        P0 *= ((l >> (5 - q)) & 1) ? sx0[q] : cx0[q];
        P1 *= ((l >> (5 - q)) & 1) ? sx1[q] : cx1[q];
    }

    __half2 v[64];
    v[0] = __floats2half2_rn(P0 * cx0[11], P1 * cx1[11]);
    v[1] = __floats2half2_rn(P0 * sx0[11], P1 * sx1[11]);
#pragma unroll
    for (int lvl = 1; lvl < 6; ++lvl) {
        const int q = 11 - lvl;
        const __half2 SX = __floats2half2_rn(sx0[q], sx1[q]);
        const __half2 CX = __floats2half2_rn(cx0[q], cx1[q]);
#pragma unroll
        for (int j = 0; j < (1 << 5); ++j) {
            if (j >= (1 << lvl)) continue;
            v[j + (1 << lvl)] = __hmul2(v[j], SX);
            v[j]              = __hmul2(v[j], CX);
        }
    }

    float Call = 1.0f;   // product of cos(w/2) over all gates (deferred scale)

    // ---- variational layers ----
#pragma unroll 1
    for (int k = 0; k < DEPTH; ++k) {
        // ---- RT1: frame A -> frame B with both CNOT groups folded ----
#pragma unroll
        for (int t = 0; t < 16; ++t) {
            uint4 w = make_uint4(h2u(v[4 * t]), h2u(v[4 * t + 1]),
                                 h2u(v[4 * t + 2]), h2u(v[4 * t + 3]));
            *(uint4*)&wrow[4 * t] = w;
        }
        // chunked reads: dst quad {4t..4t+3} reads rows {hfun&3} of window
        // hfun(4t)>>2, split 2/2 by column parity -> one read2 per (win,par)
#pragma unroll
        for (int t = 0; t < 16; ++t) {
            const int cw = hfun(4 * t) >> 2;
#pragma unroll
            for (int j = 0; j < 4; ++j) {
                const int r = 4 * t + j;
                const uint32_t* pb = (r & 1) ? bB[cw] : bA[cw];
                v[r] = u2h(pb[(hfun(r) & 3) * LSTRIDE]);
            }
        }

        // ---- shear-RY qubits 0..5 (frame B: qubit p <-> reg bit 5-p) ----
#pragma unroll
        for (int p = 0; p < 6; ++p) {
            float cw, sw;
            __sincosf(0.5f * W[k * NQ + p], &sw, &cw);
            Call *= cw;
            const float t = sw / cw;
            const __half2 T2  = __floats2half2_rn(t, t);
            const __half2 Tn2 = __floats2half2_rn(-t, -t);
            switch (p) {
                case 0: shear16<32>(v, T2, Tn2); break;
                case 1: shear16<16>(v, T2, Tn2); break;
                case 2: shear16<8>(v, T2, Tn2); break;
                case 3: shear16<4>(v, T2, Tn2); break;
                case 4: shear16<2>(v, T2, Tn2); break;
                case 5: shear16<1>(v, T2, Tn2); break;
            }
        }

        // ---- RT2: plain transpose, frame B -> frame A ----
#pragma unroll
        for (int t = 0; t < 16; ++t) {
            uint4 w = make_uint4(h2u(v[4 * t]), h2u(v[4 * t + 1]),
                                 h2u(v[4 * t + 2]), h2u(v[4 * t + 3]));
            *(uint4*)&wrow[4 * t] = w;
        }
#pragma unroll
        for (int t = 0; t < 16; ++t) {
#pragma unroll
            for (int j = 0; j < 4; ++j)
                v[4 * t + j] = u2h(bT[t][j * LSTRIDE]);
        }

        // ---- shear-RY qubits 6..11 (frame A: qubit p <-> reg bit 11-p) ----
#pragma unroll
        for (int p = 6; p < NQ; ++p) {
            float cw, sw;
            __sincosf(0.5f * W[k * NQ + p], &sw, &cw);
            Call *= cw;
            const float t = sw / cw;
            const __half2 T2  = __floats2half2_rn(t, t);
            const __half2 Tn2 = __floats2half2_rn(-t, -t);
            switch (p) {
                case 6:  shear16<32>(v, T2, Tn2); break;
                case 7:  shear16<16>(v, T2, Tn2); break;
                case 8:  shear16<8>(v, T2, Tn2); break;
                case 9:  shear16<4>(v, T2, Tn2); break;
                case 10: shear16<2>(v, T2, Tn2); break;
                case 11: shear16<1>(v, T2, Tn2); break;
            }
        }
    }

    const float C2 = (Call * Call);   // deferred |amplitude|^2 scale

    // ---- measurement (fp32): <Z_p> per sample, frame A ----
    float c20[16], c21[16];
#pragma unroll
    for (int m = 0; m < 16; ++m) {
        float a0 = 0.0f, a1 = 0.0f;
#pragma unroll
        for (int i = 0; i < 4; ++i) {
            const float2 f = __half22float2(v[4 * m + i]);
            a0 += f.x * f.x;
            a1 += f.y * f.y;
        }
        c20[m] = a0;
        c21[m] = a1;
    }

    float S0 = 0.0f, S1 = 0.0f;
#pragma unroll
    for (int m = 0; m < 16; ++m) { S0 += c20[m]; S1 += c21[m]; }
    S0 *= C2; S1 *= C2;

    float T0[4], T1[4];
#pragma unroll
    for (int t = 0; t < 4; ++t) {
        float a0 = 0.0f, a1 = 0.0f;
#pragma unroll
        for (int m = 0; m < 16; ++m) {
            const float sgn = ((m >> t) & 1) ? -1.0f : 1.0f;
            a0 += sgn * c20[m];
            a1 += sgn * c21[m];
        }
        T0[t] = a0 * C2;
        T1[t] = a1 * C2;
    }

    float o0[NCLASS], o1[NCLASS];
#pragma unroll
    for (int p = 0; p < 6; ++p) {   // qubit p on lane bit (5-p)
        const float sgn = ((l >> (5 - p)) & 1) ? -1.0f : 1.0f;
        float r0 = sgn * S0, r1 = sgn * S1;
#pragma unroll
        for (int m = 0; m < 6; ++m) { r0 += __shfl_xor(r0, 1 << m, 64); r1 += __shfl_xor(r1, 1 << m, 64); }
        o0[p] = r0; o1[p] = r1;
    }
#pragma unroll
    for (int p = 6; p < 10; ++p) {  // qubit p on reg bit (11-p) -> T[9-p]
        float r0 = T0[9 - p], r1 = T1[9 - p];
#pragma unroll
        for (int m = 0; m < 6; ++m) { r0 += __shfl_xor(r0, 1 << m, 64); r1 += __shfl_xor(r1, 1 << m, 64); }
        o0[p] = r0; o1[p] = r1;
    }

    if (lane == 0) {
#pragma unroll
        for (int p = 0; p < NCLASS; ++p) {
            out[s0 * NCLASS + p] = o0[p];
            out[s1 * NCLASS + p] = o1[p];
        }
    }
}

extern "C" void kernel_launch(void* const* d_in, const int* in_sizes, int n_in,
                              void* d_out, int out_size, void* d_ws, size_t ws_size,
                              hipStream_t stream) {
    const float* X = (const float*)d_in[0];
    const float* W = (const float*)d_in[1];
    float* out     = (float*)d_out;
    (void)in_sizes; (void)n_in; (void)out_size; (void)d_ws; (void)ws_size;

    dim3 grid(BATCH / (2 * WPB));   // 2 samples per wave, WPB waves per block
    dim3 block(WPB * 64);
    hipLaunchKernelGGL(vqc_kernel, grid, block, 0, stream, X, W, out);
}